// Round 12
// baseline (412.823 us; speedup 1.0000x reference)
//
#include <hip/hip_runtime.h>
#include <hip/hip_bf16.h>

// SE(3)-Transformer backbone, MI355X.
// Dims: B=16 N=64 FIN=16 C=32 D=4 (mg: l0=1,l1=3,l2=5,l3=7 ->16) L=4 H=8 hd=4
// f layout: [b*64+n][c][mg], 512 floats/node.
// nf layout v2 per node (2560 floats):
//   +0    q[slot]            (512)   slot = c*16+mg
//   +512  {id_k,id_v}[slot]  (1024)  interleaved pairs
//   +1536 {sc_k,sc_v}[l(slot),c(slot)] (1024) interleaved, expanded per slot
// r-column permuted order: n' = c*16 + l*4 + p  (p: 0=k-sc,1=k-id,2=v-sc,3=v-id)
//
// Round-2: NO min-waves launch_bounds. Round-9/10/11: MFMA radial GEMM, 8-edge
// tiles w/ duplicated B cols -> VGPR 92 + LDS 35KB, 82us. Round-11 FETCH=36MB
// vs 12.5MB compulsory: default block->XCD round-robin spreads every batch
// across all XCDs -> per-XCD nf working set 10.5MB >> 4MB L2 -> thrash.
// Round 12: XCD swizzle bd=(bid&7)*128+(bid>>3): each XCD owns 2 batches
// (nf slice 1.3MB, L2-resident; cross-layer reuse since epilogue writes land
// in the same XCD's L2).

typedef float  f32x4  __attribute__((ext_vector_type(4)));
typedef short  bf16x8 __attribute__((ext_vector_type(8)));

__device__ __forceinline__ int lof(int mg)   { return (mg==0)?0:((mg<4)?1:((mg<9)?2:3)); }
__device__ __forceinline__ int mgb_of(int l) { return (l==0)?0:((l==1)?1:((l==2)?4:9)); }

// ---- nodefeats v2: fl = node fiber (512, LDS) -> out = nf row (2560) ----
__device__ __forceinline__ void nf_project2(const float* fl, float* out,
    const float* __restrict__ Wk, const float* __restrict__ Wv,
    const float* __restrict__ Wq, int li, int tid, int nT) {
  for (int o = tid; o < 2560; o += nT) {
    float acc = 0.f;
    if (o < 512) {                       // q
      int c = o >> 4, mg = o & 15, l = lof(mg);
      const float* w = Wq + (size_t)((li*4 + l)*32 + c) * 32;
      #pragma unroll
      for (int i = 0; i < 32; i++) acc += w[i] * fl[i*16 + mg];
    } else if (o < 1536) {               // id_k / id_v interleaved
      int s = (o - 512) >> 1, kv = (o - 512) & 1;
      int c = s >> 4, mg = s & 15, l = lof(mg);
      const float* w = (kv ? Wv : Wk) + (size_t)(((li*4 + l)*2 + 1)*32 + c) * 32;
      #pragma unroll
      for (int i = 0; i < 32; i++) acc += w[i] * fl[i*16 + mg];
    } else {                             // sc_k / sc_v expanded per slot
      int s = (o - 1536) >> 1, kv = (o - 1536) & 1;
      int c = s >> 4, l = lof(s & 15);
      const float* w = (kv ? Wv : Wk) + (size_t)(((li*4 + l)*2 + 0)*32 + c) * 32;
      #pragma unroll
      for (int i = 0; i < 32; i++) acc += w[i] * fl[i*16];
    }
    out[o] = acc;
  }
}

// ---- prep: rw2->bf16 hi/lo (permuted), rb2 permuted, embed, nodefeats L0 ----
__global__ __launch_bounds__(256) void prep_k(const float* __restrict__ h,
    const float* __restrict__ Wemb,
    const float* __restrict__ Wk, const float* __restrict__ Wv,
    const float* __restrict__ Wq,
    const float* __restrict__ rw2, const float* __restrict__ rb2,
    float* __restrict__ f, float* __restrict__ nf,
    __hip_bfloat16* __restrict__ rw2bh, __hip_bfloat16* __restrict__ rw2bl,
    float* __restrict__ rb2p) {
  __shared__ __align__(16) float fl[512];
  const int node = blockIdx.x;
  const int tid = threadIdx.x;

  // weight conversion (blocks 0..255 cover it)
  const int gidx = blockIdx.x * 256 + tid;
  if (gidx < 65536) {              // [li][n'][k] <- rw2[li][k][l*128+p*32+c]
    int lli = gidx >> 14, rem = gidx & 16383;
    int np = rem >> 5, k = rem & 31;
    int c = np >> 4, l = (np >> 2) & 3, p = np & 3;
    float v = rw2[(size_t)lli*16384 + k*512 + l*128 + p*32 + c];
    __hip_bfloat16 hi = __float2bfloat16(v);
    __hip_bfloat16 lo = __float2bfloat16(v - __bfloat162float(hi));
    rw2bh[gidx] = hi;
    rw2bl[gidx] = lo;
  }
  if (gidx < 2048) {
    int lli = gidx >> 9, np = gidx & 511;
    int c = np >> 4, l = (np >> 2) & 3, p = np & 3;
    rb2p[gidx] = rb2[lli*512 + l*128 + p*32 + c];
  }

  fl[2*tid] = 0.f; fl[2*tid + 1] = 0.f;
  __syncthreads();
  if (tid < 32) {
    const float* hh = h + node * 16;
    float v = 0.f;
    #pragma unroll
    for (int i = 0; i < 16; i++) v += hh[i] * Wemb[i * 32 + tid];
    fl[tid * 16] = v;
  }
  __syncthreads();
  *reinterpret_cast<float2*>(f + (size_t)node * 512 + 2*tid) =
      *reinterpret_cast<const float2*>(fl + 2*tid);
  nf_project2(fl, nf + (size_t)node * 2560, Wk, Wv, Wq, 0, tid, 256);
}

// -------- fused attention layer: one block per (b,dst); one WAVE per 2 heads --------
__global__ __launch_bounds__(256) void attn_k(
    const float* __restrict__ f, const float* __restrict__ nf,
    float* __restrict__ fnext,
    const float* __restrict__ x, const int* __restrict__ bond,
    const float* __restrict__ rw1, const float* __restrict__ rb1,
    const __hip_bfloat16* __restrict__ rw2bh,
    const __hip_bfloat16* __restrict__ rw2bl,
    const float* __restrict__ rb2p,
    const float* __restrict__ Wself, const float* __restrict__ gnorm,
    const float* __restrict__ bnorm,
    const float* __restrict__ Wk, const float* __restrict__ Wv,
    const float* __restrict__ Wq,
    float* __restrict__ nf_out, int li) {
  __shared__ __align__(16) float Ysh[64][16];                 // 4KB; reused as osh
  __shared__ float rinsh[64][8];                              // 2KB; reused as facsh
  __shared__ __align__(16) float fdst[512];                   // 2KB
  __shared__ __align__(16) __hip_bfloat16 hmidb_hi[64][40];   // 5KB (pad 40)
  __shared__ __align__(16) __hip_bfloat16 hmidb_lo[64][40];   // 5KB
  __shared__ __align__(16) float rst[4][8*132];               // 16.9KB staging (8 rows)

  const int tid = threadIdx.x;
  // XCD-aware swizzle: HW dispatches block i to XCD i%8; remap so XCD x owns
  // contiguous bd range [128x, 128x+128) = batches {2x, 2x+1} (nf slice 1.3MB,
  // fits 4MB per-XCD L2; same mapping every layer -> cross-layer L2 reuse).
  const int bid = blockIdx.x;
  const int bd  = (bid & 7) * 128 + (bid >> 3);   // b*64 + d (bijective remap)
  const int b = bd >> 6, d = bd & 63;
  const int wv = tid >> 6;             // wave: heads 2wv,2wv+1; cols [128wv,128wv+128)
  const int t = tid & 63;

  // output slots (2 per lane)
  const int slot0 = 128*wv + 2*t;
  const int oc  = slot0 >> 4;
  const int mg0 = slot0 & 15, mg1 = mg0 + 1;
  const int l0 = lof(mg0), l1 = lof(mg1);

  // ---- prologue ----
  const int o0 = 2 * tid;
  *reinterpret_cast<float2*>(fdst + o0) =
      *reinterpret_cast<const float2*>(f + (size_t)bd * 512 + o0);
  const float2 qv = *reinterpret_cast<const float2*>(nf + (size_t)bd * 2560 + slot0);

  if (tid < 64) {               // geometry for source s = tid
    const int s = tid;
    const float* xb = x + (size_t)b * 192;
    float xd = xb[d*3+0], yd = xb[d*3+1], zd = xb[d*3+2];
    float dx = xb[s*3+0] - xd, dy = xb[s*3+1] - yd, dz = xb[s*3+2] - zd;
    float dist = sqrtf(dx*dx + dy*dy + dz*dz + 1e-6f);
    float inv = 1.0f / dist;
    float xx = dx*inv, yy = dy*inv, zz = dz*inv;
    float* Y = Ysh[s];
    Y[0]  = 0.28209479177387814f;
    Y[1]  = 0.4886025119029199f * yy;
    Y[2]  = 0.4886025119029199f * zz;
    Y[3]  = 0.4886025119029199f * xx;
    Y[4]  = 1.0925484305920792f * xx * yy;
    Y[5]  = 1.0925484305920792f * yy * zz;
    Y[6]  = 0.31539156525252005f * (3.0f*zz*zz - 1.0f);
    Y[7]  = 1.0925484305920792f * xx * zz;
    Y[8]  = 0.5462742152960396f * (xx*xx - yy*yy);
    Y[9]  = 0.5900435899266435f * yy * (3.0f*xx*xx - yy*yy);
    Y[10] = 2.890611442640554f  * xx * yy * zz;
    Y[11] = 0.4570457994644658f * yy * (5.0f*zz*zz - 1.0f);
    Y[12] = 0.3731763325901154f * zz * (5.0f*zz*zz - 3.0f);
    Y[13] = 0.4570457994644658f * xx * (5.0f*zz*zz - 1.0f);
    Y[14] = 1.445305721320277f  * zz * (xx*xx - yy*yy);
    Y[15] = 0.5900435899266435f * xx * (xx*xx - yy*yy);
    rinsh[s][0] = dist;
    int bt = bond[(size_t)b * 4096 + d * 64 + s];
    bt = bt < 0 ? 0 : (bt > 4 ? 4 : bt);
    rinsh[s][1] = (bt == 1) ? 1.f : 0.f;
    rinsh[s][2] = (bt == 2) ? 1.f : 0.f;
    rinsh[s][3] = (bt == 3) ? 1.f : 0.f;
    rinsh[s][4] = (bt == 4) ? 1.f : 0.f;
  }

  const int ch = tid & 31;
  float w1r[5];
  #pragma unroll
  for (int i = 0; i < 5; i++) w1r[i] = rw1[(li*5 + i)*32 + ch];
  const float b1r = rb1[li*32 + ch];

  __syncthreads();

  // ---- radial hidden (LN+relu) for all 64 edges, stored bf16 hi/lo ----
  #pragma unroll
  for (int p = 0; p < 8; p++) {
    const int e = p * 8 + (tid >> 5);
    float pre = b1r;
    #pragma unroll
    for (int i = 0; i < 5; i++) pre += rinsh[e][i] * w1r[i];
    float mu = pre;
    #pragma unroll
    for (int k = 16; k >= 1; k >>= 1) mu += __shfl_xor(mu, k, 32);
    mu *= 0.03125f;
    float dv = pre - mu;
    float var = dv * dv;
    #pragma unroll
    for (int k = 16; k >= 1; k >>= 1) var += __shfl_xor(var, k, 32);
    var *= 0.03125f;
    float hm = fmaxf(dv * rsqrtf(var + 1e-6f), 0.0f);
    __hip_bfloat16 hi = __float2bfloat16(hm);
    hmidb_hi[e][ch] = hi;
    hmidb_lo[e][ch] = __float2bfloat16(hm - __bfloat162float(hi));
  }
  __syncthreads();
  // From here: Ysh/hmidb/fdst read-only; waves fully independent (no barriers).

  const int nfb = (b * 64) * 2560;
  const float4 bA = *reinterpret_cast<const float4*>(rb2p + li*512 + oc*16 + l0*4);
  const float4 bB = *reinterpret_cast<const float4*>(rb2p + li*512 + oc*16 + l1*4);
  const int rdA = (t >> 3)*16 + l0*4;
  const int rdB = (t >> 3)*16 + l1*4;
  const int afoff = li*16384 + (128*wv + (t & 15))*32 + (t >> 4)*8;  // + ct*512
  const int bfrow = t & 7;             // B edge rows duplicated: cols 8-15 repeat 0-7
  const int bfk   = (t >> 4) * 8;
  const int myrow = t & 15;            // C-fragment edge slot; only <8 are real
  const int wcol  = (t >> 4)*4;
  float* rstw = &rst[wv][0];

  float m_run = -1e30f, l_run = 0.0f, acc0 = 0.0f, acc1 = 0.0f;

  // consume 4 edges starting at global edge eg0, staged at rows rbase..rbase+3
  auto consume4 = [&](int eg0, int rbase) {
    float4 kvv[4], svv[4];
    #pragma unroll
    for (int e2 = 0; e2 < 4; e2++) {
      const float* npp = nf + nfb + (eg0 + e2) * 2560;
      kvv[e2] = *reinterpret_cast<const float4*>(npp + 512 + 2*slot0);
      svv[e2] = *reinterpret_cast<const float4*>(npp + 1536 + 2*slot0);
    }
    float lg[4], vA[4], vB[4];
    #pragma unroll
    for (int e2 = 0; e2 < 4; e2++) {
      const int eg = eg0 + e2, row = rbase + e2;
      float4 rA = *reinterpret_cast<const float4*>(rstw + row*132 + rdA);
      float4 rB = *reinterpret_cast<const float4*>(rstw + row*132 + rdB);
      rA.x += bA.x; rA.y += bA.y; rA.z += bA.z; rA.w += bA.w;
      rB.x += bB.x; rB.y += bB.y; rB.z += bB.z; rB.w += bB.w;
      const float ym0 = Ysh[eg][mg0], ym1 = Ysh[eg][mg1];
      const float k0 = rA.x * svv[e2].x * ym0 + rA.y * kvv[e2].x;
      const float k1 = rB.x * svv[e2].z * ym1 + rB.y * kvv[e2].z;
      float pl = qv.x * k0 + qv.y * k1;
      pl += __shfl_xor(pl, 1);
      pl += __shfl_xor(pl, 2);
      pl += __shfl_xor(pl, 4);
      pl += __shfl_xor(pl, 8);
      pl += __shfl_xor(pl, 16);
      lg[e2] = (eg == d) ? -1e9f : pl * 0.125f;   // scale = 1/sqrt(hd*16)
      vA[e2] = rA.z * svv[e2].y * ym0 + rA.w * kvv[e2].y;
      vB[e2] = rB.z * svv[e2].w * ym1 + rB.w * kvv[e2].w;
    }
    const float m4 = fmaxf(fmaxf(lg[0], lg[1]), fmaxf(lg[2], lg[3]));
    const float m_new = fmaxf(m_run, m4);
    const float resc = __expf(m_run - m_new);
    acc0 *= resc; acc1 *= resc; l_run *= resc;
    #pragma unroll
    for (int e2 = 0; e2 < 4; e2++) {
      const float wgt = __expf(lg[e2] - m_new);
      l_run += wgt;
      acc0 += wgt * vA[e2];
      acc1 += wgt * vB[e2];
    }
    m_run = m_new;
  };

  for (int mt8 = 0; mt8 < 8; mt8++) {        // 8 edge-tiles of 8 (B cols duplicated)
    const int e0 = mt8 * 8;
    const bf16x8 bhi = *reinterpret_cast<const bf16x8*>(&hmidb_hi[e0 + bfrow][bfk]);
    const bf16x8 blo = *reinterpret_cast<const bf16x8*>(&hmidb_lo[e0 + bfrow][bfk]);
    // produce + stage immediately (cfr never held across consume)
    #pragma unroll
    for (int ct = 0; ct < 8; ct++) {
      const bf16x8 ah = *reinterpret_cast<const bf16x8*>(
          reinterpret_cast<const short*>(rw2bh) + afoff + ct*512);
      const bf16x8 al = *reinterpret_cast<const bf16x8*>(
          reinterpret_cast<const short*>(rw2bl) + afoff + ct*512);
      f32x4 c = {0.f, 0.f, 0.f, 0.f};
      c = __builtin_amdgcn_mfma_f32_16x16x32_bf16(al, bhi, c, 0, 0, 0);
      c = __builtin_amdgcn_mfma_f32_16x16x32_bf16(ah, blo, c, 0, 0, 0);
      c = __builtin_amdgcn_mfma_f32_16x16x32_bf16(ah, bhi, c, 0, 0, 0);
      if (myrow < 8)
        *reinterpret_cast<f32x4*>(rstw + myrow*132 + ct*16 + wcol) = c;
    }
    asm volatile("s_waitcnt lgkmcnt(0)" ::: "memory");
    __builtin_amdgcn_sched_barrier(0);
    consume4(e0,     0);
    consume4(e0 + 4, 4);
    // next tile's writes cannot bypass this tile's reads (same-wave DS in-order)
  }

  // ---- epilogue: normalize, Wself skip, NormSE3, write, next-layer nf ----
  const float invl = 1.0f / l_run;
  acc0 *= invl; acc1 *= invl;
  {
    const float* w0 = Wself + (size_t)((li*4 + l0)*32 + oc) * 32;
    const float* w1 = Wself + (size_t)((li*4 + l1)*32 + oc) * 32;
    #pragma unroll
    for (int i = 0; i < 32; i++) {
      acc0 += w0[i] * fdst[i*16 + mg0];
      acc1 += w1[i] * fdst[i*16 + mg1];
    }
  }
  __syncthreads();                     // all waves done reading Ysh
  float* osh = &Ysh[0][0];
  osh[slot0] = acc0; osh[slot0 + 1] = acc1;
  __syncthreads();
  float* facsh = &rinsh[0][0];
  if (tid < 128) {
    const int c2 = tid >> 2, l2 = tid & 3;
    const int mb = mgb_of(l2), M2 = 2*l2 + 1;
    float ss = 0.f;
    for (int m = 0; m < M2; m++) { float v = osh[c2*16 + mb + m]; ss += v*v; }
    const float nrm = sqrtf(ss + 1e-6f);
    const float gg = gnorm[(li*4 + l2)*32 + c2];
    const float bb = bnorm[(li*4 + l2)*32 + c2];
    const float sg = fmaxf(gg*nrm + bb, 0.f);
    facsh[c2*4 + l2] = sg / nrm;
  }
  __syncthreads();
  const float g0 = acc0 * facsh[oc*4 + l0];
  const float g1 = acc1 * facsh[oc*4 + l1];
  *reinterpret_cast<float2*>(fnext + (size_t)bd * 512 + slot0) = make_float2(g0, g1);

  if (nf_out) {
    osh[slot0] = g0; osh[slot0 + 1] = g1;
    __syncthreads();
    nf_project2(osh, nf_out + (size_t)bd * 2560, Wk, Wv, Wq, li + 1, tid, 256);
  }
}

// ---------------- readout ----------------
__global__ __launch_bounds__(256) void readout_k(const float* __restrict__ f,
    const float* __restrict__ Wfinal, const float* __restrict__ bfinal,
    float* __restrict__ out) {
  __shared__ float invs[2][128];
  __shared__ float inv1[128];
  const int b = blockIdx.x;
  const int tid = threadIdx.x;
  const int j = tid & 127, half = tid >> 7;
  float p = 0.f;
  for (int n = half*32; n < half*32 + 32; n++) {
    const float* fn = f + (size_t)(b*64 + n) * 512;
    float v;
    if (j < 32) {
      v = fn[j*16];
    } else {
      int l = j >> 5, c = j & 31;
      int mb = mgb_of(l), M = 2*l + 1;
      float ss = 0.f;
      for (int m = 0; m < M; m++) { float t = fn[c*16 + mb + m]; ss += t*t; }
      v = sqrtf(ss + 1e-6f);
    }
    p += v;
  }
  invs[half][j] = p;
  __syncthreads();
  if (tid < 128) inv1[tid] = (invs[0][tid] + invs[1][tid]) * (1.0f / 64.0f);
  __syncthreads();
  if (tid < 128) {
    float acc = bfinal[tid];
    for (int k = 0; k < 128; k++) acc += inv1[k] * Wfinal[k*128 + tid];
    out[b*128 + tid] = acc;
  }
}

extern "C" void kernel_launch(void* const* d_in, const int* in_sizes, int n_in,
                              void* d_out, int out_size, void* d_ws, size_t ws_size,
                              hipStream_t stream) {
  (void)in_sizes; (void)n_in; (void)out_size; (void)ws_size;
  const float* h      = (const float*)d_in[0];
  const float* x      = (const float*)d_in[1];
  const int*   bond   = (const int*)d_in[2];
  const float* Wemb   = (const float*)d_in[3];
  const float* rw1    = (const float*)d_in[4];
  const float* rb1    = (const float*)d_in[5];
  const float* rw2    = (const float*)d_in[6];
  const float* rb2    = (const float*)d_in[7];
  const float* Wk     = (const float*)d_in[8];
  const float* Wv     = (const float*)d_in[9];
  const float* Wq     = (const float*)d_in[10];
  const float* Wself  = (const float*)d_in[11];
  const float* gnorm  = (const float*)d_in[12];
  const float* bnorm  = (const float*)d_in[13];
  const float* Wfinal = (const float*)d_in[14];
  const float* bfinal = (const float*)d_in[15];
  float* out = (float*)d_out;

  float* ws  = (float*)d_ws;
  float* fA   = ws;                          // 524288
  float* fB   = fA + 524288;                 // 524288
  float* nfA  = fB + 524288;                 // 1024*2560 = 2621440
  float* nfB  = nfA + 2621440;               // 2621440
  float* rb2p = nfB + 2621440;               // 2048
  __hip_bfloat16* rw2bh = (__hip_bfloat16*)(rb2p + 2048);       // 65536 bf16
  __hip_bfloat16* rw2bl = (__hip_bfloat16*)(rb2p + 2048 + 32768); // 65536 bf16

  prep_k<<<1024, 256, 0, stream>>>(h, Wemb, Wk, Wv, Wq, rw2, rb2,
                                   fA, nfA, rw2bh, rw2bl, rb2p);

  float* fc = fA;  float* fn2 = fB;
  float* nfc = nfA; float* nfn = nfB;
  for (int li = 0; li < 4; li++) {
    attn_k<<<1024, 256, 0, stream>>>(fc, nfc, fn2, x, bond,
                                     rw1, rb1, rw2bh, rw2bl, rb2p,
                                     Wself, gnorm, bnorm, Wk, Wv, Wq,
                                     (li < 3) ? nfn : nullptr, li);
    float* t = fc; fc = fn2; fn2 = t;
    t = nfc; nfc = nfn; nfn = t;
  }

  readout_k<<<16, 256, 0, stream>>>(fc, Wfinal, bfinal, out);
}

// Round 15
// 381.497 us; speedup vs baseline: 1.0821x; 1.0821x over previous
//
#include <hip/hip_runtime.h>
#include <hip/hip_bf16.h>

// SE(3)-Transformer backbone, MI355X.
// Dims: B=16 N=64 FIN=16 C=32 D=4 (mg: l0=1,l1=3,l2=5,l3=7 ->16) L=4 H=8 hd=4
// f layout: [b*64+n][c][mg], 512 floats/node.
// nf layout v2 per node (2560 floats):
//   +0    q[slot]            (512)   slot = c*16+mg
//   +512  {id_k,id_v}[slot]  (1024)  interleaved pairs
//   +1536 {sc_k,sc_v}[l(slot),c(slot)] (1024) interleaved, expanded per slot
// r-column permuted order: n' = c*16 + l*4 + p  (p: 0=k-sc,1=k-id,2=v-sc,3=v-id)
//
// R2: NO min-waves launch_bounds. R9-11: MFMA radial GEMM (8-edge tiles,
// duplicated B cols): VGPR 92, LDS 35KB, 82us. R12: XCD swizzle -> FETCH
// 36->7MB but dur flat => latency-bound, not BW-bound. R13 (resubmitted 3rd
// time after broker timeouts — never measured): (a) software-pipeline consume
// loads (load A / produce / load B / math A / load A' / math B) so every L2
// load batch is covered by >=130 issue-cycles of work; (b) coalesced prep_k
// weight conversion (was stride-512 reads); (c) two-phase readout
// (1024-block inv pass + 16-block reduce).

typedef float  f32x4  __attribute__((ext_vector_type(4)));
typedef short  bf16x8 __attribute__((ext_vector_type(8)));

__device__ __forceinline__ int lof(int mg)   { return (mg==0)?0:((mg<4)?1:((mg<9)?2:3)); }
__device__ __forceinline__ int mgb_of(int l) { return (l==0)?0:((l==1)?1:((l==2)?4:9)); }

// ---- nodefeats v2: fl = node fiber (512, LDS) -> out = nf row (2560) ----
__device__ __forceinline__ void nf_project2(const float* fl, float* out,
    const float* __restrict__ Wk, const float* __restrict__ Wv,
    const float* __restrict__ Wq, int li, int tid, int nT) {
  for (int o = tid; o < 2560; o += nT) {
    float acc = 0.f;
    if (o < 512) {                       // q
      int c = o >> 4, mg = o & 15, l = lof(mg);
      const float* w = Wq + (size_t)((li*4 + l)*32 + c) * 32;
      #pragma unroll
      for (int i = 0; i < 32; i++) acc += w[i] * fl[i*16 + mg];
    } else if (o < 1536) {               // id_k / id_v interleaved
      int s = (o - 512) >> 1, kv = (o - 512) & 1;
      int c = s >> 4, mg = s & 15, l = lof(mg);
      const float* w = (kv ? Wv : Wk) + (size_t)(((li*4 + l)*2 + 1)*32 + c) * 32;
      #pragma unroll
      for (int i = 0; i < 32; i++) acc += w[i] * fl[i*16 + mg];
    } else {                             // sc_k / sc_v expanded per slot
      int s = (o - 1536) >> 1, kv = (o - 1536) & 1;
      int c = s >> 4, l = lof(s & 15);
      const float* w = (kv ? Wv : Wk) + (size_t)(((li*4 + l)*2 + 0)*32 + c) * 32;
      #pragma unroll
      for (int i = 0; i < 32; i++) acc += w[i] * fl[i*16];
    }
    out[o] = acc;
  }
}

// ---- prep: rw2->bf16 hi/lo (permuted, COALESCED reads), rb2 permuted,
//      embed, nodefeats L0 ----
__global__ __launch_bounds__(256) void prep_k(const float* __restrict__ h,
    const float* __restrict__ Wemb,
    const float* __restrict__ Wk, const float* __restrict__ Wv,
    const float* __restrict__ Wq,
    const float* __restrict__ rw2, const float* __restrict__ rb2,
    float* __restrict__ f, float* __restrict__ nf,
    __hip_bfloat16* __restrict__ rw2bh, __hip_bfloat16* __restrict__ rw2bl,
    float* __restrict__ rb2p) {
  __shared__ __align__(16) float fl[512];
  const int node = blockIdx.x;
  const int tid = threadIdx.x;

  // weight conversion: read rw2 LINEARLY (coalesced), scatter-write dest.
  const int gidx = blockIdx.x * 256 + tid;
  if (gidx < 65536) {
    // gidx = lli*16384 + k*512 + col, col = l*128 + p*32 + c
    int lli = gidx >> 14, rem = gidx & 16383;
    int k = rem >> 9, col = rem & 511;
    int l = col >> 7, p = (col >> 5) & 3, c = col & 31;
    int np = c*16 + l*4 + p;
    float v = rw2[gidx];
    __hip_bfloat16 hi = __float2bfloat16(v);
    __hip_bfloat16 lo = __float2bfloat16(v - __bfloat162float(hi));
    rw2bh[lli*16384 + np*32 + k] = hi;
    rw2bl[lli*16384 + np*32 + k] = lo;
  }
  if (gidx < 2048) {
    int lli = gidx >> 9, col = gidx & 511;
    int l = col >> 7, p = (col >> 5) & 3, c = col & 31;
    rb2p[lli*512 + c*16 + l*4 + p] = rb2[gidx];
  }

  fl[2*tid] = 0.f; fl[2*tid + 1] = 0.f;
  __syncthreads();
  if (tid < 32) {
    const float* hh = h + node * 16;
    float v = 0.f;
    #pragma unroll
    for (int i = 0; i < 16; i++) v += hh[i] * Wemb[i * 32 + tid];
    fl[tid * 16] = v;
  }
  __syncthreads();
  *reinterpret_cast<float2*>(f + (size_t)node * 512 + 2*tid) =
      *reinterpret_cast<const float2*>(fl + 2*tid);
  nf_project2(fl, nf + (size_t)node * 2560, Wk, Wv, Wq, 0, tid, 256);
}

// -------- fused attention layer: one block per (b,dst); one WAVE per 2 heads --------
__global__ __launch_bounds__(256) void attn_k(
    const float* __restrict__ f, const float* __restrict__ nf,
    float* __restrict__ fnext,
    const float* __restrict__ x, const int* __restrict__ bond,
    const float* __restrict__ rw1, const float* __restrict__ rb1,
    const __hip_bfloat16* __restrict__ rw2bh,
    const __hip_bfloat16* __restrict__ rw2bl,
    const float* __restrict__ rb2p,
    const float* __restrict__ Wself, const float* __restrict__ gnorm,
    const float* __restrict__ bnorm,
    const float* __restrict__ Wk, const float* __restrict__ Wv,
    const float* __restrict__ Wq,
    float* __restrict__ nf_out, int li) {
  __shared__ __align__(16) float Ysh[64][16];                 // 4KB; reused as osh
  __shared__ float rinsh[64][8];                              // 2KB; reused as facsh
  __shared__ __align__(16) float fdst[512];                   // 2KB
  __shared__ __align__(16) __hip_bfloat16 hmidb_hi[64][40];   // 5KB (pad 40)
  __shared__ __align__(16) __hip_bfloat16 hmidb_lo[64][40];   // 5KB
  __shared__ __align__(16) float rst[4][8*132];               // 16.9KB staging (8 rows)

  const int tid = threadIdx.x;
  // XCD-aware swizzle (R12): XCD x owns bd in [128x,128x+128) = 2 batches
  const int bid = blockIdx.x;
  const int bd  = (bid & 7) * 128 + (bid >> 3);
  const int b = bd >> 6, d = bd & 63;
  const int wv = tid >> 6;             // wave: heads 2wv,2wv+1; cols [128wv,128wv+128)
  const int t = tid & 63;

  // output slots (2 per lane)
  const int slot0 = 128*wv + 2*t;
  const int oc  = slot0 >> 4;
  const int mg0 = slot0 & 15, mg1 = mg0 + 1;
  const int l0 = lof(mg0), l1 = lof(mg1);

  // ---- prologue ----
  const int o0 = 2 * tid;
  *reinterpret_cast<float2*>(fdst + o0) =
      *reinterpret_cast<const float2*>(f + (size_t)bd * 512 + o0);
  const float2 qv = *reinterpret_cast<const float2*>(nf + (size_t)bd * 2560 + slot0);

  if (tid < 64) {               // geometry for source s = tid
    const int s = tid;
    const float* xb = x + (size_t)b * 192;
    float xd = xb[d*3+0], yd = xb[d*3+1], zd = xb[d*3+2];
    float dx = xb[s*3+0] - xd, dy = xb[s*3+1] - yd, dz = xb[s*3+2] - zd;
    float dist = sqrtf(dx*dx + dy*dy + dz*dz + 1e-6f);
    float inv = 1.0f / dist;
    float xx = dx*inv, yy = dy*inv, zz = dz*inv;
    float* Y = Ysh[s];
    Y[0]  = 0.28209479177387814f;
    Y[1]  = 0.4886025119029199f * yy;
    Y[2]  = 0.4886025119029199f * zz;
    Y[3]  = 0.4886025119029199f * xx;
    Y[4]  = 1.0925484305920792f * xx * yy;
    Y[5]  = 1.0925484305920792f * yy * zz;
    Y[6]  = 0.31539156525252005f * (3.0f*zz*zz - 1.0f);
    Y[7]  = 1.0925484305920792f * xx * zz;
    Y[8]  = 0.5462742152960396f * (xx*xx - yy*yy);
    Y[9]  = 0.5900435899266435f * yy * (3.0f*xx*xx - yy*yy);
    Y[10] = 2.890611442640554f  * xx * yy * zz;
    Y[11] = 0.4570457994644658f * yy * (5.0f*zz*zz - 1.0f);
    Y[12] = 0.3731763325901154f * zz * (5.0f*zz*zz - 3.0f);
    Y[13] = 0.4570457994644658f * xx * (5.0f*zz*zz - 1.0f);
    Y[14] = 1.445305721320277f  * zz * (xx*xx - yy*yy);
    Y[15] = 0.5900435899266435f * xx * (xx*xx - yy*yy);
    rinsh[s][0] = dist;
    int bt = bond[(size_t)b * 4096 + d * 64 + s];
    bt = bt < 0 ? 0 : (bt > 4 ? 4 : bt);
    rinsh[s][1] = (bt == 1) ? 1.f : 0.f;
    rinsh[s][2] = (bt == 2) ? 1.f : 0.f;
    rinsh[s][3] = (bt == 3) ? 1.f : 0.f;
    rinsh[s][4] = (bt == 4) ? 1.f : 0.f;
  }

  const int ch = tid & 31;
  float w1r[5];
  #pragma unroll
  for (int i = 0; i < 5; i++) w1r[i] = rw1[(li*5 + i)*32 + ch];
  const float b1r = rb1[li*32 + ch];

  __syncthreads();

  // ---- radial hidden (LN+relu) for all 64 edges, stored bf16 hi/lo ----
  #pragma unroll
  for (int p = 0; p < 8; p++) {
    const int e = p * 8 + (tid >> 5);
    float pre = b1r;
    #pragma unroll
    for (int i = 0; i < 5; i++) pre += rinsh[e][i] * w1r[i];
    float mu = pre;
    #pragma unroll
    for (int k = 16; k >= 1; k >>= 1) mu += __shfl_xor(mu, k, 32);
    mu *= 0.03125f;
    float dv = pre - mu;
    float var = dv * dv;
    #pragma unroll
    for (int k = 16; k >= 1; k >>= 1) var += __shfl_xor(var, k, 32);
    var *= 0.03125f;
    float hm = fmaxf(dv * rsqrtf(var + 1e-6f), 0.0f);
    __hip_bfloat16 hi = __float2bfloat16(hm);
    hmidb_hi[e][ch] = hi;
    hmidb_lo[e][ch] = __float2bfloat16(hm - __bfloat162float(hi));
  }
  __syncthreads();
  // From here: Ysh/hmidb/fdst read-only; waves fully independent (no barriers).

  const int nfb = (b * 64) * 2560;
  const float4 bA = *reinterpret_cast<const float4*>(rb2p + li*512 + oc*16 + l0*4);
  const float4 bB = *reinterpret_cast<const float4*>(rb2p + li*512 + oc*16 + l1*4);
  const int rdA = (t >> 3)*16 + l0*4;
  const int rdB = (t >> 3)*16 + l1*4;
  const int afoff = li*16384 + (128*wv + (t & 15))*32 + (t >> 4)*8;  // + ct*512
  const int bfrow = t & 7;             // B edge rows duplicated: cols 8-15 repeat 0-7
  const int bfk   = (t >> 4) * 8;
  const int myrow = t & 15;            // C-fragment edge slot; only <8 are real
  const int wcol  = (t >> 4)*4;
  float* rstw = &rst[wv][0];

  float m_run = -1e30f, l_run = 0.0f, acc0 = 0.0f, acc1 = 0.0f;

  // issue loads for 4 edges starting at eg0 into (kv, sv)
  auto load4 = [&](int eg0, float4* kv, float4* sv) {
    #pragma unroll
    for (int e2 = 0; e2 < 4; e2++) {
      const float* npp = nf + nfb + (eg0 + e2) * 2560;
      kv[e2] = *reinterpret_cast<const float4*>(npp + 512 + 2*slot0);
      sv[e2] = *reinterpret_cast<const float4*>(npp + 1536 + 2*slot0);
    }
  };
  // math for 4 edges (operands already in regs), staged at rows rbase..rbase+3
  auto math4 = [&](int eg0, int rbase, const float4* kv, const float4* sv) {
    float lg[4], vA[4], vB[4];
    #pragma unroll
    for (int e2 = 0; e2 < 4; e2++) {
      const int eg = eg0 + e2, row = rbase + e2;
      float4 rA = *reinterpret_cast<const float4*>(rstw + row*132 + rdA);
      float4 rB = *reinterpret_cast<const float4*>(rstw + row*132 + rdB);
      rA.x += bA.x; rA.y += bA.y; rA.z += bA.z; rA.w += bA.w;
      rB.x += bB.x; rB.y += bB.y; rB.z += bB.z; rB.w += bB.w;
      const float ym0 = Ysh[eg][mg0], ym1 = Ysh[eg][mg1];
      const float k0 = rA.x * sv[e2].x * ym0 + rA.y * kv[e2].x;
      const float k1 = rB.x * sv[e2].z * ym1 + rB.y * kv[e2].z;
      float pl = qv.x * k0 + qv.y * k1;
      pl += __shfl_xor(pl, 1);
      pl += __shfl_xor(pl, 2);
      pl += __shfl_xor(pl, 4);
      pl += __shfl_xor(pl, 8);
      pl += __shfl_xor(pl, 16);
      lg[e2] = (eg == d) ? -1e9f : pl * 0.125f;   // scale = 1/sqrt(hd*16)
      vA[e2] = rA.z * sv[e2].y * ym0 + rA.w * kv[e2].y;
      vB[e2] = rB.z * sv[e2].w * ym1 + rB.w * kv[e2].w;
    }
    const float m4 = fmaxf(fmaxf(lg[0], lg[1]), fmaxf(lg[2], lg[3]));
    const float m_new = fmaxf(m_run, m4);
    const float resc = __expf(m_run - m_new);
    acc0 *= resc; acc1 *= resc; l_run *= resc;
    #pragma unroll
    for (int e2 = 0; e2 < 4; e2++) {
      const float wgt = __expf(lg[e2] - m_new);
      l_run += wgt;
      acc0 += wgt * vA[e2];
      acc1 += wgt * vB[e2];
    }
    m_run = m_new;
  };

  // software pipeline: load(A) | produce | load(B) | math(A) | load(A') | math(B)
  float4 kA[4], sA[4], kB[4], sB[4];
  load4(0, kA, sA);
  for (int mt8 = 0; mt8 < 8; mt8++) {        // 8 edge-tiles of 8 (B cols duplicated)
    const int e0 = mt8 * 8;
    const bf16x8 bhi = *reinterpret_cast<const bf16x8*>(&hmidb_hi[e0 + bfrow][bfk]);
    const bf16x8 blo = *reinterpret_cast<const bf16x8*>(&hmidb_lo[e0 + bfrow][bfk]);
    // produce + stage immediately (cfr never held across consume)
    #pragma unroll
    for (int ct = 0; ct < 8; ct++) {
      const bf16x8 ah = *reinterpret_cast<const bf16x8*>(
          reinterpret_cast<const short*>(rw2bh) + afoff + ct*512);
      const bf16x8 al = *reinterpret_cast<const bf16x8*>(
          reinterpret_cast<const short*>(rw2bl) + afoff + ct*512);
      f32x4 c = {0.f, 0.f, 0.f, 0.f};
      c = __builtin_amdgcn_mfma_f32_16x16x32_bf16(al, bhi, c, 0, 0, 0);
      c = __builtin_amdgcn_mfma_f32_16x16x32_bf16(ah, blo, c, 0, 0, 0);
      c = __builtin_amdgcn_mfma_f32_16x16x32_bf16(ah, bhi, c, 0, 0, 0);
      if (myrow < 8)
        *reinterpret_cast<f32x4*>(rstw + myrow*132 + ct*16 + wcol) = c;
    }
    asm volatile("s_waitcnt lgkmcnt(0)" ::: "memory");
    __builtin_amdgcn_sched_barrier(0);
    load4(e0 + 4, kB, sB);                    // B latency hides under math(A)
    math4(e0, 0, kA, sA);
    if (mt8 < 7) load4(e0 + 8, kA, sA);       // A' latency hides under math(B)+produce
    math4(e0 + 4, 4, kB, sB);
    // next tile's ds_writes cannot bypass this tile's ds_reads (same-wave in-order)
  }

  // ---- epilogue: normalize, Wself skip, NormSE3, write, next-layer nf ----
  const float invl = 1.0f / l_run;
  acc0 *= invl; acc1 *= invl;
  {
    const float* w0 = Wself + (size_t)((li*4 + l0)*32 + oc) * 32;
    const float* w1 = Wself + (size_t)((li*4 + l1)*32 + oc) * 32;
    #pragma unroll
    for (int i = 0; i < 32; i++) {
      acc0 += w0[i] * fdst[i*16 + mg0];
      acc1 += w1[i] * fdst[i*16 + mg1];
    }
  }
  __syncthreads();                     // all waves done reading Ysh
  float* osh = &Ysh[0][0];
  osh[slot0] = acc0; osh[slot0 + 1] = acc1;
  __syncthreads();
  float* facsh = &rinsh[0][0];
  if (tid < 128) {
    const int c2 = tid >> 2, l2 = tid & 3;
    const int mb = mgb_of(l2), M2 = 2*l2 + 1;
    float ss = 0.f;
    for (int m = 0; m < M2; m++) { float v = osh[c2*16 + mb + m]; ss += v*v; }
    const float nrm = sqrtf(ss + 1e-6f);
    const float gg = gnorm[(li*4 + l2)*32 + c2];
    const float bb = bnorm[(li*4 + l2)*32 + c2];
    const float sg = fmaxf(gg*nrm + bb, 0.f);
    facsh[c2*4 + l2] = sg / nrm;
  }
  __syncthreads();
  const float g0 = acc0 * facsh[oc*4 + l0];
  const float g1 = acc1 * facsh[oc*4 + l1];
  *reinterpret_cast<float2*>(fnext + (size_t)bd * 512 + slot0) = make_float2(g0, g1);

  if (nf_out) {
    osh[slot0] = g0; osh[slot0 + 1] = g1;
    __syncthreads();
    nf_project2(osh, nf_out + (size_t)bd * 2560, Wk, Wv, Wq, li + 1, tid, 256);
  }
}

// ---------------- readout phase 1: per-node invariant features ----------------
__global__ __launch_bounds__(128) void readout1_k(const float* __restrict__ f,
    float* __restrict__ invbuf) {
  const int node = blockIdx.x;       // 1024
  const int j = threadIdx.x;         // 128
  const float* fn = f + (size_t)node * 512;
  float v;
  if (j < 32) {
    v = fn[j*16];
  } else {
    int l = j >> 5, c = j & 31;
    int mb = mgb_of(l), M = 2*l + 1;
    float ss = 0.f;
    for (int m = 0; m < M; m++) { float t2 = fn[c*16 + mb + m]; ss += t2*t2; }
    v = sqrtf(ss + 1e-6f);
  }
  invbuf[(size_t)node * 128 + j] = v;
}

// ---------------- readout phase 2: mean over nodes -> Wfinal ----------------
__global__ __launch_bounds__(128) void readout2_k(const float* __restrict__ invbuf,
    const float* __restrict__ Wfinal, const float* __restrict__ bfinal,
    float* __restrict__ out) {
  __shared__ float inv1[128];
  const int b = blockIdx.x;          // 16
  const int tid = threadIdx.x;       // 128
  float p = 0.f;
  for (int n = 0; n < 64; n++)
    p += invbuf[(size_t)(b*64 + n) * 128 + tid];
  inv1[tid] = p * (1.0f / 64.0f);
  __syncthreads();
  float acc = bfinal[tid];
  for (int k = 0; k < 128; k++) acc += inv1[k] * Wfinal[k*128 + tid];
  out[b*128 + tid] = acc;
}

extern "C" void kernel_launch(void* const* d_in, const int* in_sizes, int n_in,
                              void* d_out, int out_size, void* d_ws, size_t ws_size,
                              hipStream_t stream) {
  (void)in_sizes; (void)n_in; (void)out_size; (void)ws_size;
  const float* h      = (const float*)d_in[0];
  const float* x      = (const float*)d_in[1];
  const int*   bond   = (const int*)d_in[2];
  const float* Wemb   = (const float*)d_in[3];
  const float* rw1    = (const float*)d_in[4];
  const float* rb1    = (const float*)d_in[5];
  const float* rw2    = (const float*)d_in[6];
  const float* rb2    = (const float*)d_in[7];
  const float* Wk     = (const float*)d_in[8];
  const float* Wv     = (const float*)d_in[9];
  const float* Wq     = (const float*)d_in[10];
  const float* Wself  = (const float*)d_in[11];
  const float* gnorm  = (const float*)d_in[12];
  const float* bnorm  = (const float*)d_in[13];
  const float* Wfinal = (const float*)d_in[14];
  const float* bfinal = (const float*)d_in[15];
  float* out = (float*)d_out;

  float* ws  = (float*)d_ws;
  float* fA   = ws;                          // 524288
  float* fB   = fA + 524288;                 // 524288
  float* nfA  = fB + 524288;                 // 1024*2560 = 2621440
  float* nfB  = nfA + 2621440;               // 2621440
  float* rb2p = nfB + 2621440;               // 2048
  __hip_bfloat16* rw2bh = (__hip_bfloat16*)(rb2p + 2048);       // 65536 bf16
  __hip_bfloat16* rw2bl = (__hip_bfloat16*)(rb2p + 2048 + 32768); // 65536 bf16

  prep_k<<<1024, 256, 0, stream>>>(h, Wemb, Wk, Wv, Wq, rw2, rb2,
                                   fA, nfA, rw2bh, rw2bl, rb2p);

  float* fc = fA;  float* fn2 = fB;
  float* nfc = nfA; float* nfn = nfB;
  for (int li = 0; li < 4; li++) {
    attn_k<<<1024, 256, 0, stream>>>(fc, nfc, fn2, x, bond,
                                     rw1, rb1, rw2bh, rw2bl, rb2p,
                                     Wself, gnorm, bnorm, Wk, Wv, Wq,
                                     (li < 3) ? nfn : nullptr, li);
    float* t = fc; fc = fn2; fn2 = t;
    t = nfc; nfc = nfn; nfn = t;
  }

  // nfn is the nf buffer NOT read by the last layer -> free scratch for invbuf
  float* invbuf = nfn;                       // needs 1024*128 = 131072 floats
  readout1_k<<<1024, 128, 0, stream>>>(fc, invbuf);
  readout2_k<<<16, 128, 0, stream>>>(invbuf, Wfinal, bfinal, out);
}